// Round 8
// baseline (181.993 us; speedup 1.0000x reference)
//
#include <hip/hip_runtime.h>
#include <hip/hip_bf16.h>

// Sliding-window attention block: x@Wqkv^T -> flash-attn(window=256, causal) -> @Wproj^T
// T=4096, D=1024, H=16, Hd=64. All MFMA in bf16.

#define T_SEQ   4096
#define DM      1024
#define NH      16
#define HD      64
#define WIN     256

typedef unsigned short u16_t;
typedef u16_t  u16v8 __attribute__((ext_vector_type(8)));
typedef __bf16 bf16v8 __attribute__((ext_vector_type(8)));
typedef float  f32v4 __attribute__((ext_vector_type(4)));

__device__ __forceinline__ f32v4 mfma_bf16(u16v8 a, u16v8 b, f32v4 c) {
    return __builtin_amdgcn_mfma_f32_16x16x32_bf16(
        __builtin_bit_cast(bf16v8, a), __builtin_bit_cast(bf16v8, b), c, 0, 0, 0);
}

__device__ __forceinline__ u16_t f2bf(float f) {
    unsigned u = __builtin_bit_cast(unsigned, f);
    u += 0x7fffu + ((u >> 16) & 1u);            // RNE
    return (u16_t)(u >> 16);
}

__device__ __forceinline__ float exp2_fast(float x) {
    return __builtin_amdgcn_exp2f(x);            // v_exp_f32 (base-2)
}

__device__ __forceinline__ void gload_lds16(const u16_t* g, u16_t* l) {
    __builtin_amdgcn_global_load_lds(
        (const __attribute__((address_space(1))) unsigned int*)g,
        (__attribute__((address_space(3))) unsigned int*)l, 16, 0, 0);
}

// ---------------- fp32 -> bf16 convert (8 elems/thread) ----------------
__global__ void cvt_kernel(const float* __restrict__ in, u16_t* __restrict__ out, int n8) {
    int i = blockIdx.x * blockDim.x + threadIdx.x;
    if (i >= n8) return;
    const float4* p = (const float4*)(in + (size_t)i * 8);
    float4 a = p[0], b = p[1];
    u16v8 o;
    o[0] = f2bf(a.x); o[1] = f2bf(a.y); o[2] = f2bf(a.z); o[3] = f2bf(a.w);
    o[4] = f2bf(b.x); o[5] = f2bf(b.y); o[6] = f2bf(b.z); o[7] = f2bf(b.w);
    *(u16v8*)(out + (size_t)i * 8) = o;
}

// ---------------- bf16 GEMM v3: 4-slot K-slice ring, counted vmcnt ----------------
// C[M,N] = A[M,K] * B[N,K]^T.  K split into 32-wide slices; LDS ring of 4 slices
// (slot = s & 3).  Per slice: vmcnt(8) [slices s+1,s+2 in flight] -> barrier ->
// issue slice s+3 (4 gload_lds/wave) -> 12 ds_read_b128 -> 32 MFMA.
// Ledger: slot (s+3)&3 last read at slice s-1 (reads done before this barrier);
// vmcnt(8) guarantees slice s landed (oldest 4 loads drained).  Issue-to-consume
// distance = 3 slices.  Swizzle: chunk' = c ^ ((row>>1)&3) -> 8 lanes/bank (free).
template <int BM, int BN, int WN, int WAVES, typename OutT>
__global__ __launch_bounds__(WAVES * 64, 2)
void gemm_ring(const u16_t* __restrict__ A, const u16_t* __restrict__ B,
               OutT* __restrict__ C, int M, int N, int K) {
    constexpr int WM  = WAVES / WN;
    constexpr int PWM = BM / WM;           // per-wave rows
    constexpr int PWN = BN / WN;           // per-wave cols
    constexpr int M_F = PWM / 16, N_F = PWN / 16;
    constexpr int N_H = N_F / 2;
    constexpr int THREADS = WAVES * 64;
    constexpr int RP = THREADS / 4;        // rows staged per pass (4 chunk-threads/row)

    __shared__ u16_t lA[4 * BM * 32];
    __shared__ u16_t lB[4 * BN * 32];

    const int tid = threadIdx.x;
    const int l = tid & 63, w = tid >> 6;
    const int lr = l & 15, g = l >> 4;
    const int wrh = w / WN, wcq = w % WN;
    const int arow0 = blockIdx.y * BM, bcol0 = blockIdx.x * BN;
    const int rq = tid >> 2, cq = tid & 3;
    const int NS = K >> 5;

    f32v4 acc[M_F][N_F];
#pragma unroll
    for (int m = 0; m < M_F; ++m)
#pragma unroll
        for (int n = 0; n < N_F; ++n) acc[m][n] = f32v4{0.f, 0.f, 0.f, 0.f};

#define GSTAGE(s_)                                                                      \
    do {                                                                                \
        const int k0_ = (s_) << 5, sl_ = (s_) & 3;                                      \
        _Pragma("unroll")                                                               \
        for (int p = 0; p < BM / RP; ++p) {                                             \
            int r = rq + p * RP;                                                        \
            int cs = cq ^ ((r >> 1) & 3);                                               \
            gload_lds16(A + (size_t)(arow0 + r) * K + k0_ + cs * 8,                     \
                        lA + sl_ * (BM * 32) + r * 32 + cq * 8);                        \
        }                                                                               \
        _Pragma("unroll")                                                               \
        for (int p = 0; p < BN / RP; ++p) {                                             \
            int r = rq + p * RP;                                                        \
            int cs = cq ^ ((r >> 1) & 3);                                               \
            gload_lds16(B + (size_t)(bcol0 + r) * K + k0_ + cs * 8,                     \
                        lB + sl_ * (BN * 32) + r * 32 + cq * 8);                        \
        }                                                                               \
    } while (0)

    GSTAGE(0); GSTAGE(1); GSTAGE(2);

    for (int s = 0; s < NS; ++s) {
        if (s < NS - 2)       { asm volatile("s_waitcnt vmcnt(8)" ::: "memory"); }
        else if (s == NS - 2) { asm volatile("s_waitcnt vmcnt(4)" ::: "memory"); }
        else                  { asm volatile("s_waitcnt vmcnt(0)" ::: "memory"); }
        __builtin_amdgcn_s_barrier();
        __builtin_amdgcn_sched_barrier(0);
        if (s + 3 < NS) GSTAGE(s + 3);

        const u16_t* sA = lA + (s & 3) * (BM * 32);
        const u16_t* sB = lB + (s & 3) * (BN * 32);
        u16v8 a[M_F], b[N_F];
#pragma unroll
        for (int mf = 0; mf < M_F; ++mf) {
            int row = wrh * PWM + mf * 16 + lr;
            a[mf] = *(const u16v8*)(sA + row * 32 + (g ^ ((row >> 1) & 3)) * 8);
        }
#pragma unroll
        for (int nf = 0; nf < N_H; ++nf) {
            int row = wcq * PWN + nf * 16 + lr;
            b[nf] = *(const u16v8*)(sB + row * 32 + (g ^ ((row >> 1) & 3)) * 8);
        }
        __builtin_amdgcn_s_setprio(1);
#pragma unroll
        for (int mf = 0; mf < M_F; ++mf)
#pragma unroll
            for (int nf = 0; nf < N_H; ++nf)
                acc[mf][nf] = mfma_bf16(a[mf], b[nf], acc[mf][nf]);
        __builtin_amdgcn_s_setprio(0);
#pragma unroll
        for (int nf = N_H; nf < N_F; ++nf) {
            int row = wcq * PWN + nf * 16 + lr;
            b[nf] = *(const u16v8*)(sB + row * 32 + (g ^ ((row >> 1) & 3)) * 8);
        }
        __builtin_amdgcn_s_setprio(1);
#pragma unroll
        for (int mf = 0; mf < M_F; ++mf)
#pragma unroll
            for (int nf = N_H; nf < N_F; ++nf)
                acc[mf][nf] = mfma_bf16(a[mf], b[nf], acc[mf][nf]);
        __builtin_amdgcn_s_setprio(0);
    }
#undef GSTAGE

    // epilogue: C/D layout col=lane&15, row=(lane>>4)*4+j (m89-verified)
#pragma unroll
    for (int mf = 0; mf < M_F; ++mf) {
        int crow0 = arow0 + wrh * PWM + mf * 16 + g * 4;
#pragma unroll
        for (int nf = 0; nf < N_F; ++nf) {
            int ccol = bcol0 + wcq * PWN + nf * 16 + lr;
#pragma unroll
            for (int j = 0; j < 4; ++j) {
                float v = acc[mf][nf][j];
                if constexpr (sizeof(OutT) == 2)
                    C[(size_t)(crow0 + j) * N + ccol] = (OutT)f2bf(v);
                else
                    C[(size_t)(crow0 + j) * N + ccol] = (OutT)v;
            }
        }
    }
}

// ---------------- V transpose: qkv[t][2048+h*64+d] -> vt[h][d][t] ----------------
__global__ __launch_bounds__(256) void vtrans_kernel(const u16_t* __restrict__ qkv,
                                                     u16_t* __restrict__ vt) {
    __shared__ u16_t tile[64][72];   // +8 pad
    const int t0 = blockIdx.x * 64, h = blockIdx.y;
    const int tid = threadIdx.x;
    {
        int r = tid >> 2, c = (tid & 3) * 16;
        const u16_t* src = qkv + (size_t)(t0 + r) * (3 * DM) + 2 * DM + h * HD + c;
        *(u16v8*)&tile[r][c]     = *(const u16v8*)src;
        *(u16v8*)&tile[r][c + 8] = *(const u16v8*)(src + 8);
    }
    __syncthreads();
    {
        int d = tid >> 2, ts = (tid & 3) * 16;
        u16_t* dst = vt + ((size_t)h * HD + d) * T_SEQ + t0 + ts;
        u16v8 o0, o1;
#pragma unroll
        for (int i = 0; i < 8; ++i) { o0[i] = tile[ts + i][d]; o1[i] = tile[ts + 8 + i][d]; }
        *(u16v8*)dst       = o0;
        *(u16v8*)(dst + 8) = o1;
    }
}

// ---------------- flash attention, sliding window (v2, unchanged) ----------------
__global__ __launch_bounds__(256) void attn_kernel(const u16_t* __restrict__ qkv,
                                                   const u16_t* __restrict__ vt,
                                                   u16_t* __restrict__ out) {
    __shared__ u16_t lK[2][64 * 64];
    __shared__ u16_t lV[2][64 * 64];
    __shared__ u16_t pbuf[4][16 * 64];

    const int h = blockIdx.y;
    const int q0 = blockIdx.x * 64;
    const int tid = threadIdx.x;
    const int w = tid >> 6, l = tid & 63;
    const int lr = l & 15, g = l >> 4;
    const int i0 = q0 + w * 16;
    u16_t* P = pbuf[w];

    const int r_st = tid >> 3;          // 0..31
    const int c8l  = tid & 7;
    const u16_t* kBase = qkv + DM + h * HD;                 // row stride 3*DM
    const u16_t* vBase = vt + (size_t)h * HD * T_SEQ;       // row stride T_SEQ

    u16v8 qf0, qf1;
    {
        const u16_t* qrow = qkv + h * HD + (size_t)(i0 + lr) * (3 * DM) + g * 8;
        qf0 = *(const u16v8*)qrow;
        qf1 = *(const u16v8*)(qrow + 32);
    }
    f32v4 o[4];
#pragma unroll
    for (int n = 0; n < 4; ++n) o[n] = f32v4{0.f, 0.f, 0.f, 0.f};
    float m_run[4], l_run[4];
#pragma unroll
    for (int j = 0; j < 4; ++j) { m_run[j] = -1e30f; l_run[j] = 0.f; }

    const int c0 = (q0 >= WIN) ? q0 - WIN : 0;
    const int nch = ((q0 - c0) >> 6) + 1;

#define STAGE_KV(buf, cc)                                                              \
    do {                                                                               \
        _Pragma("unroll")                                                              \
        for (int p = 0; p < 2; ++p) {                                                  \
            int rr = r_st + p * 32;                                                    \
            int cs = c8l ^ (rr & 7);                                                   \
            gload_lds16(kBase + (size_t)(cc + rr) * (3 * DM) + cs * 8,                 \
                        lK[buf] + (size_t)(rr * 64 + c8l * 8));                        \
            gload_lds16(vBase + (size_t)rr * T_SEQ + (cc) + cs * 8,                    \
                        lV[buf] + (size_t)(rr * 64 + c8l * 8));                        \
        }                                                                              \
    } while (0)

    STAGE_KV(0, c0);

    const float sc = 0.125f * 1.4426950408889634f;   // Hd^-0.5 * log2(e)

    for (int ci = 0; ci < nch; ++ci) {
        const int c = c0 + (ci << 6);
        const int cur = ci & 1;
        __syncthreads();
        if (ci + 1 < nch) STAGE_KV(cur ^ 1, c + 64);

        const u16_t* K = lK[cur];
        const u16_t* V = lV[cur];

        f32v4 s[4];
#pragma unroll
        for (int kt = 0; kt < 4; ++kt) {
            int krow = kt * 16 + lr;
            u16v8 k0 = *(const u16v8*)(K + krow * 64 + ((g     ^ (krow & 7)) * 8));
            u16v8 k1 = *(const u16v8*)(K + krow * 64 + (((4+g) ^ (krow & 7)) * 8));
            f32v4 z = f32v4{0.f, 0.f, 0.f, 0.f};
            z = mfma_bf16(qf0, k0, z);
            z = mfma_bf16(qf1, k1, z);
            s[kt] = z;
        }

        const bool full = (c + 63 <= i0) && (c >= i0 - 240);   // wave-uniform
        if (full) {
#pragma unroll
            for (int kt = 0; kt < 4; ++kt)
#pragma unroll
                for (int j = 0; j < 4; ++j) s[kt][j] *= sc;
        } else {
#pragma unroll
            for (int j = 0; j < 4; ++j) {
                const int i = i0 + g * 4 + j;
#pragma unroll
                for (int kt = 0; kt < 4; ++kt) {
                    const int jg = c + kt * 16 + lr;
                    float v = s[kt][j] * sc;
                    const bool okm = (jg <= i) && (jg >= i - (WIN - 1));
                    s[kt][j] = okm ? v : -3e38f;
                }
            }
        }

        float mloc[4], corr[4], rsum[4];
#pragma unroll
        for (int j = 0; j < 4; ++j)
            mloc[j] = fmaxf(fmaxf(s[0][j], s[1][j]), fmaxf(s[2][j], s[3][j]));
#pragma unroll
        for (int d = 1; d < 16; d <<= 1)
#pragma unroll
            for (int j = 0; j < 4; ++j) mloc[j] = fmaxf(mloc[j], __shfl_xor(mloc[j], d, 64));
#pragma unroll
        for (int j = 0; j < 4; ++j) {
            float mnew = fmaxf(m_run[j], mloc[j]);
            corr[j] = exp2_fast(m_run[j] - mnew);
            m_run[j] = mnew;
            rsum[j] = 0.f;
        }
#pragma unroll
        for (int kt = 0; kt < 4; ++kt)
#pragma unroll
            for (int j = 0; j < 4; ++j) {
                float p = exp2_fast(s[kt][j] - m_run[j]);
                rsum[j] += p;
                int rP = g * 4 + j;
                int col = kt * 16 + lr;
                int c8 = col >> 3;
                P[rP * 64 + ((c8 ^ (rP & 7)) * 8 + (col & 7))] = f2bf(p);
            }
#pragma unroll
        for (int d = 1; d < 16; d <<= 1)
#pragma unroll
            for (int j = 0; j < 4; ++j) rsum[j] += __shfl_xor(rsum[j], d, 64);
#pragma unroll
        for (int j = 0; j < 4; ++j) l_run[j] = l_run[j] * corr[j] + rsum[j];
#pragma unroll
        for (int n = 0; n < 4; ++n)
#pragma unroll
            for (int j = 0; j < 4; ++j) o[n][j] *= corr[j];

        u16v8 pa0 = *(const u16v8*)(P + lr * 64 + ((g     ^ (lr & 7)) * 8));
        u16v8 pa1 = *(const u16v8*)(P + lr * 64 + (((4+g) ^ (lr & 7)) * 8));
#pragma unroll
        for (int n = 0; n < 4; ++n) {
            int vrow = n * 16 + lr;
            u16v8 v0 = *(const u16v8*)(V + vrow * 64 + ((g     ^ (vrow & 7)) * 8));
            u16v8 v1 = *(const u16v8*)(V + vrow * 64 + (((4+g) ^ (vrow & 7)) * 8));
            o[n] = mfma_bf16(pa0, v0, o[n]);
            o[n] = mfma_bf16(pa1, v1, o[n]);
        }
    }
#undef STAGE_KV

#pragma unroll
    for (int n = 0; n < 4; ++n)
#pragma unroll
        for (int j = 0; j < 4; ++j) {
            int t = i0 + g * 4 + j;
            out[(size_t)t * DM + h * HD + n * 16 + lr] = f2bf(o[n][j] / l_run[j]);
        }
}

extern "C" void kernel_launch(void* const* d_in, const int* in_sizes, int n_in,
                              void* d_out, int out_size, void* d_ws, size_t ws_size,
                              hipStream_t stream) {
    const float* x     = (const float*)d_in[0];
    const float* wqkv  = (const float*)d_in[1];
    const float* wproj = (const float*)d_in[2];
    float* out = (float*)d_out;
    char* ws = (char*)d_ws;

    u16_t* xb     = (u16_t*)(ws);                        // 8 MB  [0,8M)
    u16_t* wqkvb  = (u16_t*)(ws + (size_t)(8u << 20));   // 6 MB
    u16_t* wprojb = (u16_t*)(ws + (size_t)(14u << 20));  // 2 MB
    u16_t* qkvb   = (u16_t*)(ws + (size_t)(16u << 20));  // 24 MB
    u16_t* vt     = (u16_t*)(ws + (size_t)(40u << 20));  // 8 MB
    u16_t* attnb  = (u16_t*)(ws);                        // overlays xb (x dead after QKV GEMM)

    const int n8x = T_SEQ * DM / 8, n8q = 3 * DM * DM / 8, n8p = DM * DM / 8;
    cvt_kernel<<<(n8x + 255) / 256, 256, 0, stream>>>(x, xb, n8x);
    cvt_kernel<<<(n8q + 255) / 256, 256, 0, stream>>>(wqkv, wqkvb, n8q);
    cvt_kernel<<<(n8p + 255) / 256, 256, 0, stream>>>(wproj, wprojb, n8p);

    // QKV GEMM: 256x256 tile, 8 waves, K-slice ring
    gemm_ring<256, 256, 4, 8, u16_t><<<dim3(3 * DM / 256, T_SEQ / 256), 512, 0, stream>>>(
        xb, wqkvb, qkvb, T_SEQ, 3 * DM, DM);

    vtrans_kernel<<<dim3(T_SEQ / 64, NH), 256, 0, stream>>>(qkvb, vt);

    attn_kernel<<<dim3(T_SEQ / 64, NH), 256, 0, stream>>>(qkvb, vt, attnb);

    // proj GEMM: 128x128 tile, 4 waves, K-slice ring (64KB LDS -> 2 blocks/CU)
    gemm_ring<128, 128, 2, 4, float><<<dim3(DM / 128, T_SEQ / 128), 256, 0, stream>>>(
        attnb, wprojb, out, T_SEQ, DM, DM);
}

// Round 11
// 165.139 us; speedup vs baseline: 1.1021x; 1.1021x over previous
//
#include <hip/hip_runtime.h>
#include <hip/hip_bf16.h>

// Sliding-window attention block: x@Wqkv^T -> flash-attn(window=256, causal) -> @Wproj^T
// T=4096, D=1024, H=16, Hd=64. All MFMA in bf16.

#define T_SEQ   4096
#define DM      1024
#define NH      16
#define HD      64
#define WIN     256

typedef unsigned short u16_t;
typedef u16_t  u16v8 __attribute__((ext_vector_type(8)));
typedef __bf16 bf16v8 __attribute__((ext_vector_type(8)));
typedef float  f32v4 __attribute__((ext_vector_type(4)));

__device__ __forceinline__ f32v4 mfma_bf16(u16v8 a, u16v8 b, f32v4 c) {
    return __builtin_amdgcn_mfma_f32_16x16x32_bf16(
        __builtin_bit_cast(bf16v8, a), __builtin_bit_cast(bf16v8, b), c, 0, 0, 0);
}

__device__ __forceinline__ u16_t f2bf(float f) {
    unsigned u = __builtin_bit_cast(unsigned, f);
    u += 0x7fffu + ((u >> 16) & 1u);            // RNE
    return (u16_t)(u >> 16);
}

__device__ __forceinline__ float exp2_fast(float x) {
    return __builtin_amdgcn_exp2f(x);            // v_exp_f32 (base-2)
}

__device__ __forceinline__ void gload_lds16(const u16_t* g, u16_t* l) {
    __builtin_amdgcn_global_load_lds(
        (const __attribute__((address_space(1))) unsigned int*)g,
        (__attribute__((address_space(3))) unsigned int*)l, 16, 0, 0);
}

// ---------------- fp32 -> bf16 convert (8 elems/thread) ----------------
__global__ void cvt_kernel(const float* __restrict__ in, u16_t* __restrict__ out, int n8) {
    int i = blockIdx.x * blockDim.x + threadIdx.x;
    if (i >= n8) return;
    const float4* p = (const float4*)(in + (size_t)i * 8);
    float4 a = p[0], b = p[1];
    u16v8 o;
    o[0] = f2bf(a.x); o[1] = f2bf(a.y); o[2] = f2bf(a.z); o[3] = f2bf(a.w);
    o[4] = f2bf(b.x); o[5] = f2bf(b.y); o[6] = f2bf(b.z); o[7] = f2bf(b.w);
    *(u16v8*)(out + (size_t)i * 8) = o;
}

// ---------------- bf16 GEMM v4: T3-minimum 2-phase, BK=32, double-buffered ----------
// C[M,N] = A[M,K] * B[N,K]^T.  Per K-tile t: issue STAGE(t+1) into other buffer
// FIRST, then ds_read + MFMA tile t (full-tile latency cover), then one
// __syncthreads (implicit vmcnt(0)+lgkmcnt(0) drain) per tile.  Small LDS
// (2 buffers, BK=32) keeps 2-3 blocks/CU for inter-block overlap (m114).
// Swizzle: chunk' = chunk ^ ((row>>1)&3), both-sides -> 0 bank conflicts (measured r5/r8).
template <int BM, int BN, int WN, int WAVES, int MW, typename OutT>
__global__ __launch_bounds__(WAVES * 64, MW)
void gemm2p(const u16_t* __restrict__ A, const u16_t* __restrict__ B,
            OutT* __restrict__ C, int M, int N, int K) {
    constexpr int WM  = WAVES / WN;
    constexpr int PWM = BM / WM;           // per-wave rows
    constexpr int PWN = BN / WN;           // per-wave cols
    constexpr int M_F = PWM / 16, N_F = PWN / 16;
    constexpr int THREADS = WAVES * 64;
    constexpr int RPP = THREADS / 4;       // rows staged per pass (4 chunk-threads/row)

    __shared__ u16_t lA[2][BM * 32];
    __shared__ u16_t lB[2][BN * 32];

    const int tid = threadIdx.x;
    const int l = tid & 63, w = tid >> 6;
    const int lr = l & 15, g = l >> 4;
    const int wrh = w / WN, wcq = w % WN;
    const int arow0 = blockIdx.y * BM, bcol0 = blockIdx.x * BN;
    const int rq = tid >> 2, cq = tid & 3;
    const int NT = K >> 5;

    f32v4 acc[M_F][N_F];
#pragma unroll
    for (int m = 0; m < M_F; ++m)
#pragma unroll
        for (int n = 0; n < N_F; ++n) acc[m][n] = f32v4{0.f, 0.f, 0.f, 0.f};

#define GSTAGE(buf, kt0)                                                                \
    do {                                                                                \
        _Pragma("unroll")                                                               \
        for (int p = 0; p < BM / RPP; ++p) {                                            \
            int r = rq + p * RPP;                                                       \
            int cs = cq ^ ((r >> 1) & 3);                                               \
            gload_lds16(A + (size_t)(arow0 + r) * K + (kt0) + cs * 8,                   \
                        lA[buf] + r * 32 + cq * 8);                                     \
        }                                                                               \
        _Pragma("unroll")                                                               \
        for (int p = 0; p < BN / RPP; ++p) {                                            \
            int r = rq + p * RPP;                                                       \
            int cs = cq ^ ((r >> 1) & 3);                                               \
            gload_lds16(B + (size_t)(bcol0 + r) * K + (kt0) + cs * 8,                   \
                        lB[buf] + r * 32 + cq * 8);                                     \
        }                                                                               \
    } while (0)

    GSTAGE(0, 0);
    __syncthreads();

    for (int t = 0; t < NT; ++t) {
        // phase A: issue next tile's staging loads FIRST (hide HBM under this tile's compute)
        if (t + 1 < NT) GSTAGE((t + 1) & 1, (t + 1) << 5);
        __builtin_amdgcn_sched_barrier(0);    // keep issue order: stage before ds_read

        // phase B: compute tile t
        const u16_t* sA = lA[t & 1];
        const u16_t* sB = lB[t & 1];
        u16v8 a[M_F], b[N_F];
#pragma unroll
        for (int mf = 0; mf < M_F; ++mf) {
            int row = wrh * PWM + mf * 16 + lr;
            a[mf] = *(const u16v8*)(sA + row * 32 + (g ^ ((row >> 1) & 3)) * 8);
        }
#pragma unroll
        for (int nf = 0; nf < N_F; ++nf) {
            int row = wcq * PWN + nf * 16 + lr;
            b[nf] = *(const u16v8*)(sB + row * 32 + (g ^ ((row >> 1) & 3)) * 8);
        }
        __builtin_amdgcn_s_setprio(1);
#pragma unroll
        for (int mf = 0; mf < M_F; ++mf)
#pragma unroll
            for (int nf = 0; nf < N_F; ++nf)
                acc[mf][nf] = mfma_bf16(a[mf], b[nf], acc[mf][nf]);
        __builtin_amdgcn_s_setprio(0);

        __syncthreads();   // drains vmcnt (t+1 staged) + lgkmcnt; buffers safe to flip
    }
#undef GSTAGE

    // epilogue: C/D layout col=lane&15, row=(lane>>4)*4+j (m89-verified)
#pragma unroll
    for (int mf = 0; mf < M_F; ++mf) {
        int crow0 = arow0 + wrh * PWM + mf * 16 + g * 4;
#pragma unroll
        for (int nf = 0; nf < N_F; ++nf) {
            int ccol = bcol0 + wcq * PWN + nf * 16 + lr;
#pragma unroll
            for (int j = 0; j < 4; ++j) {
                float v = acc[mf][nf][j];
                if constexpr (sizeof(OutT) == 2)
                    C[(size_t)(crow0 + j) * N + ccol] = (OutT)f2bf(v);
                else
                    C[(size_t)(crow0 + j) * N + ccol] = (OutT)v;
            }
        }
    }
}

// ---------------- V transpose: qkv[t][2048+h*64+d] -> vt[h][d][t] ----------------
__global__ __launch_bounds__(256) void vtrans_kernel(const u16_t* __restrict__ qkv,
                                                     u16_t* __restrict__ vt) {
    __shared__ u16_t tile[64][72];   // +8 pad
    const int t0 = blockIdx.x * 64, h = blockIdx.y;
    const int tid = threadIdx.x;
    {
        int r = tid >> 2, c = (tid & 3) * 16;
        const u16_t* src = qkv + (size_t)(t0 + r) * (3 * DM) + 2 * DM + h * HD + c;
        *(u16v8*)&tile[r][c]     = *(const u16v8*)src;
        *(u16v8*)&tile[r][c + 8] = *(const u16v8*)(src + 8);
    }
    __syncthreads();
    {
        int d = tid >> 2, ts = (tid & 3) * 16;
        u16_t* dst = vt + ((size_t)h * HD + d) * T_SEQ + t0 + ts;
        u16v8 o0, o1;
#pragma unroll
        for (int i = 0; i < 8; ++i) { o0[i] = tile[ts + i][d]; o1[i] = tile[ts + 8 + i][d]; }
        *(u16v8*)dst       = o0;
        *(u16v8*)(dst + 8) = o1;
    }
}

// ---------------- flash attention, sliding window (v2, unchanged) ----------------
__global__ __launch_bounds__(256) void attn_kernel(const u16_t* __restrict__ qkv,
                                                   const u16_t* __restrict__ vt,
                                                   u16_t* __restrict__ out) {
    __shared__ u16_t lK[2][64 * 64];
    __shared__ u16_t lV[2][64 * 64];
    __shared__ u16_t pbuf[4][16 * 64];

    const int h = blockIdx.y;
    const int q0 = blockIdx.x * 64;
    const int tid = threadIdx.x;
    const int w = tid >> 6, l = tid & 63;
    const int lr = l & 15, g = l >> 4;
    const int i0 = q0 + w * 16;
    u16_t* P = pbuf[w];

    const int r_st = tid >> 3;          // 0..31
    const int c8l  = tid & 7;
    const u16_t* kBase = qkv + DM + h * HD;                 // row stride 3*DM
    const u16_t* vBase = vt + (size_t)h * HD * T_SEQ;       // row stride T_SEQ

    u16v8 qf0, qf1;
    {
        const u16_t* qrow = qkv + h * HD + (size_t)(i0 + lr) * (3 * DM) + g * 8;
        qf0 = *(const u16v8*)qrow;
        qf1 = *(const u16v8*)(qrow + 32);
    }
    f32v4 o[4];
#pragma unroll
    for (int n = 0; n < 4; ++n) o[n] = f32v4{0.f, 0.f, 0.f, 0.f};
    float m_run[4], l_run[4];
#pragma unroll
    for (int j = 0; j < 4; ++j) { m_run[j] = -1e30f; l_run[j] = 0.f; }

    const int c0 = (q0 >= WIN) ? q0 - WIN : 0;
    const int nch = ((q0 - c0) >> 6) + 1;

#define STAGE_KV(buf, cc)                                                              \
    do {                                                                               \
        _Pragma("unroll")                                                              \
        for (int p = 0; p < 2; ++p) {                                                  \
            int rr = r_st + p * 32;                                                    \
            int cs = c8l ^ (rr & 7);                                                   \
            gload_lds16(kBase + (size_t)(cc + rr) * (3 * DM) + cs * 8,                 \
                        lK[buf] + (size_t)(rr * 64 + c8l * 8));                        \
            gload_lds16(vBase + (size_t)rr * T_SEQ + (cc) + cs * 8,                    \
                        lV[buf] + (size_t)(rr * 64 + c8l * 8));                        \
        }                                                                              \
    } while (0)

    STAGE_KV(0, c0);

    const float sc = 0.125f * 1.4426950408889634f;   // Hd^-0.5 * log2(e)

    for (int ci = 0; ci < nch; ++ci) {
        const int c = c0 + (ci << 6);
        const int cur = ci & 1;
        __syncthreads();
        if (ci + 1 < nch) STAGE_KV(cur ^ 1, c + 64);

        const u16_t* K = lK[cur];
        const u16_t* V = lV[cur];

        f32v4 s[4];
#pragma unroll
        for (int kt = 0; kt < 4; ++kt) {
            int krow = kt * 16 + lr;
            u16v8 k0 = *(const u16v8*)(K + krow * 64 + ((g     ^ (krow & 7)) * 8));
            u16v8 k1 = *(const u16v8*)(K + krow * 64 + (((4+g) ^ (krow & 7)) * 8));
            f32v4 z = f32v4{0.f, 0.f, 0.f, 0.f};
            z = mfma_bf16(qf0, k0, z);
            z = mfma_bf16(qf1, k1, z);
            s[kt] = z;
        }

        const bool full = (c + 63 <= i0) && (c >= i0 - 240);   // wave-uniform
        if (full) {
#pragma unroll
            for (int kt = 0; kt < 4; ++kt)
#pragma unroll
                for (int j = 0; j < 4; ++j) s[kt][j] *= sc;
        } else {
#pragma unroll
            for (int j = 0; j < 4; ++j) {
                const int i = i0 + g * 4 + j;
#pragma unroll
                for (int kt = 0; kt < 4; ++kt) {
                    const int jg = c + kt * 16 + lr;
                    float v = s[kt][j] * sc;
                    const bool okm = (jg <= i) && (jg >= i - (WIN - 1));
                    s[kt][j] = okm ? v : -3e38f;
                }
            }
        }

        float mloc[4], corr[4], rsum[4];
#pragma unroll
        for (int j = 0; j < 4; ++j)
            mloc[j] = fmaxf(fmaxf(s[0][j], s[1][j]), fmaxf(s[2][j], s[3][j]));
#pragma unroll
        for (int d = 1; d < 16; d <<= 1)
#pragma unroll
            for (int j = 0; j < 4; ++j) mloc[j] = fmaxf(mloc[j], __shfl_xor(mloc[j], d, 64));
#pragma unroll
        for (int j = 0; j < 4; ++j) {
            float mnew = fmaxf(m_run[j], mloc[j]);
            corr[j] = exp2_fast(m_run[j] - mnew);
            m_run[j] = mnew;
            rsum[j] = 0.f;
        }
#pragma unroll
        for (int kt = 0; kt < 4; ++kt)
#pragma unroll
            for (int j = 0; j < 4; ++j) {
                float p = exp2_fast(s[kt][j] - m_run[j]);
                rsum[j] += p;
                int rP = g * 4 + j;
                int col = kt * 16 + lr;
                int c8 = col >> 3;
                P[rP * 64 + ((c8 ^ (rP & 7)) * 8 + (col & 7))] = f2bf(p);
            }
#pragma unroll
        for (int d = 1; d < 16; d <<= 1)
#pragma unroll
            for (int j = 0; j < 4; ++j) rsum[j] += __shfl_xor(rsum[j], d, 64);
#pragma unroll
        for (int j = 0; j < 4; ++j) l_run[j] = l_run[j] * corr[j] + rsum[j];
#pragma unroll
        for (int n = 0; n < 4; ++n)
#pragma unroll
            for (int j = 0; j < 4; ++j) o[n][j] *= corr[j];

        u16v8 pa0 = *(const u16v8*)(P + lr * 64 + ((g     ^ (lr & 7)) * 8));
        u16v8 pa1 = *(const u16v8*)(P + lr * 64 + (((4+g) ^ (lr & 7)) * 8));
#pragma unroll
        for (int n = 0; n < 4; ++n) {
            int vrow = n * 16 + lr;
            u16v8 v0 = *(const u16v8*)(V + vrow * 64 + ((g     ^ (vrow & 7)) * 8));
            u16v8 v1 = *(const u16v8*)(V + vrow * 64 + (((4+g) ^ (vrow & 7)) * 8));
            o[n] = mfma_bf16(pa0, v0, o[n]);
            o[n] = mfma_bf16(pa1, v1, o[n]);
        }
    }
#undef STAGE_KV

#pragma unroll
    for (int n = 0; n < 4; ++n)
#pragma unroll
        for (int j = 0; j < 4; ++j) {
            int t = i0 + g * 4 + j;
            out[(size_t)t * DM + h * HD + n * 16 + lr] = f2bf(o[n][j] / l_run[j]);
        }
}

extern "C" void kernel_launch(void* const* d_in, const int* in_sizes, int n_in,
                              void* d_out, int out_size, void* d_ws, size_t ws_size,
                              hipStream_t stream) {
    const float* x     = (const float*)d_in[0];
    const float* wqkv  = (const float*)d_in[1];
    const float* wproj = (const float*)d_in[2];
    float* out = (float*)d_out;
    char* ws = (char*)d_ws;

    u16_t* xb     = (u16_t*)(ws);                        // 8 MB  [0,8M)
    u16_t* wqkvb  = (u16_t*)(ws + (size_t)(8u << 20));   // 6 MB
    u16_t* wprojb = (u16_t*)(ws + (size_t)(14u << 20));  // 2 MB
    u16_t* qkvb   = (u16_t*)(ws + (size_t)(16u << 20));  // 24 MB
    u16_t* vt     = (u16_t*)(ws + (size_t)(40u << 20));  // 8 MB
    u16_t* attnb  = (u16_t*)(ws);                        // overlays xb (x dead after QKV GEMM)

    const int n8x = T_SEQ * DM / 8, n8q = 3 * DM * DM / 8, n8p = DM * DM / 8;
    cvt_kernel<<<(n8x + 255) / 256, 256, 0, stream>>>(x, xb, n8x);
    cvt_kernel<<<(n8q + 255) / 256, 256, 0, stream>>>(wqkv, wqkvb, n8q);
    cvt_kernel<<<(n8p + 255) / 256, 256, 0, stream>>>(wproj, wprojb, n8p);

    // QKV GEMM: 128x128 tile, 4 waves, 2-phase dbuf (32KB LDS -> 3 blocks/CU, grid 768)
    gemm2p<128, 128, 2, 4, 3, u16_t><<<dim3(3 * DM / 128, T_SEQ / 128), 256, 0, stream>>>(
        xb, wqkvb, qkvb, T_SEQ, 3 * DM, DM);

    vtrans_kernel<<<dim3(T_SEQ / 64, NH), 256, 0, stream>>>(qkvb, vt);

    attn_kernel<<<dim3(T_SEQ / 64, NH), 256, 0, stream>>>(qkvb, vt, attnb);

    // proj GEMM: 64x128 tile, 4 waves, 2-phase dbuf (24KB LDS, grid 512 -> 2 blocks/CU)
    gemm2p<64, 128, 2, 4, 2, float><<<dim3(DM / 128, T_SEQ / 64), 256, 0, stream>>>(
        attnb, wprojb, out, T_SEQ, DM, DM);
}

// Round 12
// 158.223 us; speedup vs baseline: 1.1502x; 1.0437x over previous
//
#include <hip/hip_runtime.h>
#include <hip/hip_bf16.h>

// Sliding-window attention block: x@Wqkv^T -> flash-attn(window=256, causal) -> @Wproj^T
// T=4096, D=1024, H=16, Hd=64. All MFMA in bf16.

#define T_SEQ   4096
#define DM      1024
#define NH      16
#define HD      64
#define WIN     256

typedef unsigned short u16_t;
typedef u16_t  u16v4 __attribute__((ext_vector_type(4)));
typedef u16_t  u16v8 __attribute__((ext_vector_type(8)));
typedef __bf16 bf16v8 __attribute__((ext_vector_type(8)));
typedef float  f32v4 __attribute__((ext_vector_type(4)));

__device__ __forceinline__ f32v4 mfma_bf16(u16v8 a, u16v8 b, f32v4 c) {
    return __builtin_amdgcn_mfma_f32_16x16x32_bf16(
        __builtin_bit_cast(bf16v8, a), __builtin_bit_cast(bf16v8, b), c, 0, 0, 0);
}

__device__ __forceinline__ u16_t f2bf(float f) {
    unsigned u = __builtin_bit_cast(unsigned, f);
    u += 0x7fffu + ((u >> 16) & 1u);            // RNE
    return (u16_t)(u >> 16);
}

__device__ __forceinline__ float exp2_fast(float x) {
    return __builtin_amdgcn_exp2f(x);            // v_exp_f32 (base-2)
}

__device__ __forceinline__ void gload_lds16(const u16_t* g, u16_t* l) {
    __builtin_amdgcn_global_load_lds(
        (const __attribute__((address_space(1))) unsigned int*)g,
        (__attribute__((address_space(3))) unsigned int*)l, 16, 0, 0);
}

// ---------------- fused fp32 -> bf16 convert for all 3 inputs ----------------
#define N8X (T_SEQ * DM / 8)
#define N8Q (3 * DM * DM / 8)
#define N8P (DM * DM / 8)
__global__ void cvt3_kernel(const float* __restrict__ x, const float* __restrict__ wqkv,
                            const float* __restrict__ wproj, u16_t* __restrict__ xb,
                            u16_t* __restrict__ wqkvb, u16_t* __restrict__ wprojb) {
    int i = blockIdx.x * blockDim.x + threadIdx.x;
    const float* src; u16_t* dst; int off;
    if (i < N8X)            { src = x;     dst = xb;     off = i; }
    else if (i < N8X + N8Q) { src = wqkv;  dst = wqkvb;  off = i - N8X; }
    else                    { src = wproj; dst = wprojb; off = i - N8X - N8Q; }
    const float4* p = (const float4*)(src + (size_t)off * 8);
    float4 a = p[0], b = p[1];
    u16v8 o;
    o[0] = f2bf(a.x); o[1] = f2bf(a.y); o[2] = f2bf(a.z); o[3] = f2bf(a.w);
    o[4] = f2bf(b.x); o[5] = f2bf(b.y); o[6] = f2bf(b.z); o[7] = f2bf(b.w);
    *(u16v8*)(dst + (size_t)off * 8) = o;
}

// ---------------- bf16 GEMM v4: T3-minimum 2-phase, BK=32, double-buffered ----------
// C[M,N] = A[M,K] * B[N,K]^T.  Per K-tile t: issue STAGE(t+1) into other buffer FIRST,
// then ds_read + MFMA tile t, then one __syncthreads per tile.  Swizzle:
// chunk' = chunk ^ ((row>>1)&3), both-sides -> 0 bank conflicts (measured r5/r8).
// VT mode (QKV GEMM): blocks with bcol0 >= 2*DM hold V columns; their epilogue writes
// the TRANSPOSED tensor vt[(ccol-2048)][t] directly (4 consecutive t per lane ->
// one aligned ushort4 store), replacing the separate vtrans kernel.  qkvb's V region
// is never read, so it is not written.
template <int BM, int BN, int WN, int WAVES, int MW, bool VT, typename OutT>
__global__ __launch_bounds__(WAVES * 64, MW)
void gemm2p(const u16_t* __restrict__ A, const u16_t* __restrict__ B,
            OutT* __restrict__ C, u16_t* __restrict__ vtp, int M, int N, int K) {
    constexpr int WM  = WAVES / WN;
    constexpr int PWM = BM / WM;           // per-wave rows
    constexpr int PWN = BN / WN;           // per-wave cols
    constexpr int M_F = PWM / 16, N_F = PWN / 16;
    constexpr int THREADS = WAVES * 64;
    constexpr int RPP = THREADS / 4;       // rows staged per pass (4 chunk-threads/row)

    __shared__ u16_t lA[2][BM * 32];
    __shared__ u16_t lB[2][BN * 32];

    const int tid = threadIdx.x;
    const int l = tid & 63, w = tid >> 6;
    const int lr = l & 15, g = l >> 4;
    const int wrh = w / WN, wcq = w % WN;
    const int arow0 = blockIdx.y * BM, bcol0 = blockIdx.x * BN;
    const int rq = tid >> 2, cq = tid & 3;
    const int NT = K >> 5;

    f32v4 acc[M_F][N_F];
#pragma unroll
    for (int m = 0; m < M_F; ++m)
#pragma unroll
        for (int n = 0; n < N_F; ++n) acc[m][n] = f32v4{0.f, 0.f, 0.f, 0.f};

#define GSTAGE(buf, kt0)                                                                \
    do {                                                                                \
        _Pragma("unroll")                                                               \
        for (int p = 0; p < BM / RPP; ++p) {                                            \
            int r = rq + p * RPP;                                                       \
            int cs = cq ^ ((r >> 1) & 3);                                               \
            gload_lds16(A + (size_t)(arow0 + r) * K + (kt0) + cs * 8,                   \
                        lA[buf] + r * 32 + cq * 8);                                     \
        }                                                                               \
        _Pragma("unroll")                                                               \
        for (int p = 0; p < BN / RPP; ++p) {                                            \
            int r = rq + p * RPP;                                                       \
            int cs = cq ^ ((r >> 1) & 3);                                               \
            gload_lds16(B + (size_t)(bcol0 + r) * K + (kt0) + cs * 8,                   \
                        lB[buf] + r * 32 + cq * 8);                                     \
        }                                                                               \
    } while (0)

    GSTAGE(0, 0);
    __syncthreads();

    for (int t = 0; t < NT; ++t) {
        // phase A: issue next tile's staging loads FIRST (hide HBM under this tile's compute)
        if (t + 1 < NT) GSTAGE((t + 1) & 1, (t + 1) << 5);
        __builtin_amdgcn_sched_barrier(0);    // keep issue order: stage before ds_read

        // phase B: compute tile t
        const u16_t* sA = lA[t & 1];
        const u16_t* sB = lB[t & 1];
        u16v8 a[M_F], b[N_F];
#pragma unroll
        for (int mf = 0; mf < M_F; ++mf) {
            int row = wrh * PWM + mf * 16 + lr;
            a[mf] = *(const u16v8*)(sA + row * 32 + (g ^ ((row >> 1) & 3)) * 8);
        }
#pragma unroll
        for (int nf = 0; nf < N_F; ++nf) {
            int row = wcq * PWN + nf * 16 + lr;
            b[nf] = *(const u16v8*)(sB + row * 32 + (g ^ ((row >> 1) & 3)) * 8);
        }
        __builtin_amdgcn_s_setprio(1);
#pragma unroll
        for (int mf = 0; mf < M_F; ++mf)
#pragma unroll
            for (int nf = 0; nf < N_F; ++nf)
                acc[mf][nf] = mfma_bf16(a[mf], b[nf], acc[mf][nf]);
        __builtin_amdgcn_s_setprio(0);

        __syncthreads();   // drains vmcnt (t+1 staged) + lgkmcnt; buffers safe to flip
    }
#undef GSTAGE

    // epilogue: C/D layout col=lane&15, row=(lane>>4)*4+j (m89-verified)
    if (VT && bcol0 >= 2 * DM) {
        // V block: write transposed vt[(ccol-2048)][t], 4 consecutive t per lane
#pragma unroll
        for (int mf = 0; mf < M_F; ++mf) {
            int crow0 = arow0 + wrh * PWM + mf * 16 + g * 4;
#pragma unroll
            for (int nf = 0; nf < N_F; ++nf) {
                int ccol = bcol0 + wcq * PWN + nf * 16 + lr;
                u16v4 v4;
#pragma unroll
                for (int j = 0; j < 4; ++j) v4[j] = f2bf(acc[mf][nf][j]);
                *(u16v4*)(vtp + (size_t)(ccol - 2 * DM) * T_SEQ + crow0) = v4;
            }
        }
    } else {
#pragma unroll
        for (int mf = 0; mf < M_F; ++mf) {
            int crow0 = arow0 + wrh * PWM + mf * 16 + g * 4;
#pragma unroll
            for (int nf = 0; nf < N_F; ++nf) {
                int ccol = bcol0 + wcq * PWN + nf * 16 + lr;
#pragma unroll
                for (int j = 0; j < 4; ++j) {
                    float v = acc[mf][nf][j];
                    if constexpr (sizeof(OutT) == 2)
                        C[(size_t)(crow0 + j) * N + ccol] = (OutT)f2bf(v);
                    else
                        C[(size_t)(crow0 + j) * N + ccol] = (OutT)v;
                }
            }
        }
    }
}

// ---------------- flash attention, sliding window (v2, unchanged) ----------------
__global__ __launch_bounds__(256) void attn_kernel(const u16_t* __restrict__ qkv,
                                                   const u16_t* __restrict__ vt,
                                                   u16_t* __restrict__ out) {
    __shared__ u16_t lK[2][64 * 64];
    __shared__ u16_t lV[2][64 * 64];
    __shared__ u16_t pbuf[4][16 * 64];

    const int h = blockIdx.y;
    const int q0 = blockIdx.x * 64;
    const int tid = threadIdx.x;
    const int w = tid >> 6, l = tid & 63;
    const int lr = l & 15, g = l >> 4;
    const int i0 = q0 + w * 16;
    u16_t* P = pbuf[w];

    const int r_st = tid >> 3;          // 0..31
    const int c8l  = tid & 7;
    const u16_t* kBase = qkv + DM + h * HD;                 // row stride 3*DM
    const u16_t* vBase = vt + (size_t)h * HD * T_SEQ;       // row stride T_SEQ

    u16v8 qf0, qf1;
    {
        const u16_t* qrow = qkv + h * HD + (size_t)(i0 + lr) * (3 * DM) + g * 8;
        qf0 = *(const u16v8*)qrow;
        qf1 = *(const u16v8*)(qrow + 32);
    }
    f32v4 o[4];
#pragma unroll
    for (int n = 0; n < 4; ++n) o[n] = f32v4{0.f, 0.f, 0.f, 0.f};
    float m_run[4], l_run[4];
#pragma unroll
    for (int j = 0; j < 4; ++j) { m_run[j] = -1e30f; l_run[j] = 0.f; }

    const int c0 = (q0 >= WIN) ? q0 - WIN : 0;
    const int nch = ((q0 - c0) >> 6) + 1;

#define STAGE_KV(buf, cc)                                                              \
    do {                                                                               \
        _Pragma("unroll")                                                              \
        for (int p = 0; p < 2; ++p) {                                                  \
            int rr = r_st + p * 32;                                                    \
            int cs = c8l ^ (rr & 7);                                                   \
            gload_lds16(kBase + (size_t)(cc + rr) * (3 * DM) + cs * 8,                 \
                        lK[buf] + (size_t)(rr * 64 + c8l * 8));                        \
            gload_lds16(vBase + (size_t)rr * T_SEQ + (cc) + cs * 8,                    \
                        lV[buf] + (size_t)(rr * 64 + c8l * 8));                        \
        }                                                                              \
    } while (0)

    STAGE_KV(0, c0);

    const float sc = 0.125f * 1.4426950408889634f;   // Hd^-0.5 * log2(e)

    for (int ci = 0; ci < nch; ++ci) {
        const int c = c0 + (ci << 6);
        const int cur = ci & 1;
        __syncthreads();
        if (ci + 1 < nch) STAGE_KV(cur ^ 1, c + 64);

        const u16_t* K = lK[cur];
        const u16_t* V = lV[cur];

        f32v4 s[4];
#pragma unroll
        for (int kt = 0; kt < 4; ++kt) {
            int krow = kt * 16 + lr;
            u16v8 k0 = *(const u16v8*)(K + krow * 64 + ((g     ^ (krow & 7)) * 8));
            u16v8 k1 = *(const u16v8*)(K + krow * 64 + (((4+g) ^ (krow & 7)) * 8));
            f32v4 z = f32v4{0.f, 0.f, 0.f, 0.f};
            z = mfma_bf16(qf0, k0, z);
            z = mfma_bf16(qf1, k1, z);
            s[kt] = z;
        }

        const bool full = (c + 63 <= i0) && (c >= i0 - 240);   // wave-uniform
        if (full) {
#pragma unroll
            for (int kt = 0; kt < 4; ++kt)
#pragma unroll
                for (int j = 0; j < 4; ++j) s[kt][j] *= sc;
        } else {
#pragma unroll
            for (int j = 0; j < 4; ++j) {
                const int i = i0 + g * 4 + j;
#pragma unroll
                for (int kt = 0; kt < 4; ++kt) {
                    const int jg = c + kt * 16 + lr;
                    float v = s[kt][j] * sc;
                    const bool okm = (jg <= i) && (jg >= i - (WIN - 1));
                    s[kt][j] = okm ? v : -3e38f;
                }
            }
        }

        float mloc[4], corr[4], rsum[4];
#pragma unroll
        for (int j = 0; j < 4; ++j)
            mloc[j] = fmaxf(fmaxf(s[0][j], s[1][j]), fmaxf(s[2][j], s[3][j]));
#pragma unroll
        for (int d = 1; d < 16; d <<= 1)
#pragma unroll
            for (int j = 0; j < 4; ++j) mloc[j] = fmaxf(mloc[j], __shfl_xor(mloc[j], d, 64));
#pragma unroll
        for (int j = 0; j < 4; ++j) {
            float mnew = fmaxf(m_run[j], mloc[j]);
            corr[j] = exp2_fast(m_run[j] - mnew);
            m_run[j] = mnew;
            rsum[j] = 0.f;
        }
#pragma unroll
        for (int kt = 0; kt < 4; ++kt)
#pragma unroll
            for (int j = 0; j < 4; ++j) {
                float p = exp2_fast(s[kt][j] - m_run[j]);
                rsum[j] += p;
                int rP = g * 4 + j;
                int col = kt * 16 + lr;
                int c8 = col >> 3;
                P[rP * 64 + ((c8 ^ (rP & 7)) * 8 + (col & 7))] = f2bf(p);
            }
#pragma unroll
        for (int d = 1; d < 16; d <<= 1)
#pragma unroll
            for (int j = 0; j < 4; ++j) rsum[j] += __shfl_xor(rsum[j], d, 64);
#pragma unroll
        for (int j = 0; j < 4; ++j) l_run[j] = l_run[j] * corr[j] + rsum[j];
#pragma unroll
        for (int n = 0; n < 4; ++n)
#pragma unroll
            for (int j = 0; j < 4; ++j) o[n][j] *= corr[j];

        u16v8 pa0 = *(const u16v8*)(P + lr * 64 + ((g     ^ (lr & 7)) * 8));
        u16v8 pa1 = *(const u16v8*)(P + lr * 64 + (((4+g) ^ (lr & 7)) * 8));
#pragma unroll
        for (int n = 0; n < 4; ++n) {
            int vrow = n * 16 + lr;
            u16v8 v0 = *(const u16v8*)(V + vrow * 64 + ((g     ^ (vrow & 7)) * 8));
            u16v8 v1 = *(const u16v8*)(V + vrow * 64 + (((4+g) ^ (vrow & 7)) * 8));
            o[n] = mfma_bf16(pa0, v0, o[n]);
            o[n] = mfma_bf16(pa1, v1, o[n]);
        }
    }
#undef STAGE_KV

#pragma unroll
    for (int n = 0; n < 4; ++n)
#pragma unroll
        for (int j = 0; j < 4; ++j) {
            int t = i0 + g * 4 + j;
            out[(size_t)t * DM + h * HD + n * 16 + lr] = f2bf(o[n][j] / l_run[j]);
        }
}

extern "C" void kernel_launch(void* const* d_in, const int* in_sizes, int n_in,
                              void* d_out, int out_size, void* d_ws, size_t ws_size,
                              hipStream_t stream) {
    const float* x     = (const float*)d_in[0];
    const float* wqkv  = (const float*)d_in[1];
    const float* wproj = (const float*)d_in[2];
    float* out = (float*)d_out;
    char* ws = (char*)d_ws;

    u16_t* xb     = (u16_t*)(ws);                        // 8 MB  [0,8M)
    u16_t* wqkvb  = (u16_t*)(ws + (size_t)(8u << 20));   // 6 MB
    u16_t* wprojb = (u16_t*)(ws + (size_t)(14u << 20));  // 2 MB
    u16_t* qkvb   = (u16_t*)(ws + (size_t)(16u << 20));  // 24 MB
    u16_t* vt     = (u16_t*)(ws + (size_t)(40u << 20));  // 8 MB
    u16_t* attnb  = (u16_t*)(ws);                        // overlays xb (x dead after QKV GEMM)

    // fused cvt: x, Wqkv, Wproj -> bf16 (one launch)
    cvt3_kernel<<<(N8X + N8Q + N8P + 255) / 256, 256, 0, stream>>>(
        x, wqkv, wproj, xb, wqkvb, wprojb);

    // QKV GEMM: 128x128 tile, 2-phase dbuf; V blocks (bcol0>=2048) write vt transposed
    gemm2p<128, 128, 2, 4, 3, true, u16_t><<<dim3(3 * DM / 128, T_SEQ / 128), 256, 0, stream>>>(
        xb, wqkvb, qkvb, vt, T_SEQ, 3 * DM, DM);

    attn_kernel<<<dim3(T_SEQ / 64, NH), 256, 0, stream>>>(qkvb, vt, attnb);

    // proj GEMM: 64x128 tile, 2-phase dbuf
    gemm2p<64, 128, 2, 4, 2, false, float><<<dim3(DM / 128, T_SEQ / 64), 256, 0, stream>>>(
        attnb, wprojb, out, nullptr, T_SEQ, DM, DM);
}